// Round 3
// baseline (112038.171 us; speedup 1.0000x reference)
//
#include <hip/hip_runtime.h>
#include <hip/hip_cooperative_groups.h>

namespace cg = cooperative_groups;

static constexpr int NB = 64, NT = 256, NE = 1024, NH = 1024, NL = 3;
static constexpr int STATE = NL * NB * NH;    // 196608
static constexpr int NBLK = 512;              // grid blocks (2 per CU)
static constexpr int NTHR = 512;              // threads per block (8 waves)
static constexpr int NWAVE = 8;
static constexpr int KSLICE = 256;            // k per wave (1024 per part / 4 waves)

// One-time transpose of inputs (B,T,E) -> xT (T,E,B) for coalesced reads.
__global__ void xpose_kernel(const float* __restrict__ x, float* __restrict__ xT) {
    __shared__ float tile[64][65];
    const int bx = blockIdx.x;            // T * (E/64) = 256*16 = 4096 blocks
    const int t  = bx >> 4;
    const int et = bx & 15;
    const int tid = threadIdx.x;          // 256 threads
    {
        const int e = tid & 63, bq = tid >> 6;
        #pragma unroll
        for (int i = 0; i < 16; ++i) {
            const int b = bq * 16 + i;
            tile[b][e] = x[(size_t)b * (NT * NE) + (size_t)t * NE + et * 64 + e];
        }
    }
    __syncthreads();
    {
        const int b = tid & 63, eq = tid >> 6;
        #pragma unroll
        for (int i = 0; i < 16; ++i) {
            const int e = eq * 16 + i;
            xT[((size_t)t * NE + et * 64 + e) * 64 + b] = tile[b][e];
        }
    }
}

// Per-wave dot: one activation scalar (coalesced across lanes) feeds 8 rows
// (2 n-values x 4 gates). Weight pointers are wave-uniform -> scalar loads.
template<int ASTRIDE>
__device__ __forceinline__ void dot8(const float* __restrict__ act,
                                     const float* const wp[8], float acc[8]) {
    #pragma unroll 4
    for (int k = 0; k < KSLICE; ++k) {
        const float av = act[(size_t)k * ASTRIDE];
        #pragma unroll
        for (int j = 0; j < 8; ++j) acc[j] = fmaf(av, wp[j][k], acc[j]);
    }
}

// grid: 512 blocks x 512 threads (8 waves). block = 2 adjacent n values.
// Waves 0-3: x-part K-slices; waves 4-7: h-part K-slices. LDS reduce.
__global__ void __launch_bounds__(NTHR, 4)
lstm_kernel(const float* __restrict__ inputs,   // (B,T,E)
            const float* __restrict__ enc,      // (1,B,H)
            const float* __restrict__ W_ih,     // (L,4H,E)
            const float* __restrict__ W_hh,     // (L,4H,H)
            const float* __restrict__ bias,     // (L,4H)
            float* __restrict__ out,            // hT | cT | outs
            const float* __restrict__ xT,       // (T,E,B) or unused
            float* __restrict__ h0b,            // (L,H,B) transposed h buf 0
            float* __restrict__ h1b,            // (L,H,B) transposed h buf 1
            float* __restrict__ cbuf,           // (L,H,B) transposed c
            int use_xT)
{
    cg::grid_group grid = cg::this_grid();
    const int tid = threadIdx.x;
    const int b   = tid & 63;
    const int w   = __builtin_amdgcn_readfirstlane(tid >> 6);  // 0..7
    const int n0  = blockIdx.x * 2;

    float* hT   = out;
    float* cT   = out + STATE;
    float* outs = out + 2 * STATE;

    __shared__ float part[NWAVE][8][64];   // 16 KiB
    __shared__ float gsum[8][64];          // 2 KiB

    // init: h0 = tile(enc, L) transposed, c0 = 0
    for (int i = blockIdx.x * NTHR + tid; i < STATE; i += NBLK * NTHR) {
        const int bb = i & 63, nn = (i >> 6) & (NH - 1);
        h0b[i]  = enc[bb * NH + nn];
        cbuf[i] = 0.0f;
    }
    grid.sync();

    for (int t = 0; t < NT; ++t) {
        float* hprev = (t & 1) ? h1b : h0b;
        float* hcur  = (t & 1) ? h0b : h1b;
        for (int l = 0; l < NL; ++l) {
            const bool xpart = (w < 4);
            const int  kk    = (xpart ? w : (w - 4)) * KSLICE;
            const float* wbase = xpart
                ? W_ih + (size_t)l * (4 * NH * NE)
                : W_hh + (size_t)l * (4 * NH * NH);
            const float* wp[8];
            #pragma unroll
            for (int j = 0; j < 8; ++j) {
                const int g  = j & 3;
                const int nn = n0 + (j >> 2);
                wp[j] = wbase + ((size_t)(g * NH + nn)) * 1024 + kk;
            }
            float acc[8] = {0, 0, 0, 0, 0, 0, 0, 0};
            if (xpart) {
                if (l == 0) {
                    if (use_xT) {
                        dot8<64>(xT + ((size_t)t * NE + kk) * 64 + b, wp, acc);
                    } else {
                        dot8<1>(inputs + (size_t)b * (NT * NE) + (size_t)t * NE + kk, wp, acc);
                    }
                } else {
                    dot8<64>(hcur + ((size_t)(l - 1) * NH + kk) * 64 + b, wp, acc);
                }
            } else {
                dot8<64>(hprev + ((size_t)l * NH + kk) * 64 + b, wp, acc);
            }
            #pragma unroll
            for (int j = 0; j < 8; ++j) part[w][j][b] = acc[j];
            __syncthreads();

            {                                      // one thread per (nl,g,b)
                const int j  = tid >> 6;           // nl*4 + g
                const int bb = tid & 63;
                float s = 0.0f;
                #pragma unroll
                for (int ww = 0; ww < NWAVE; ++ww) s += part[ww][j][bb];
                const int g  = j & 3;
                const int nn = n0 + (j >> 2);
                gsum[j][bb] = s + bias[(size_t)l * (4 * NH) + g * NH + nn];
            }
            __syncthreads();

            if (tid < 128) {                       // one thread per (nl,b)
                const int nl = tid >> 6, bb = tid & 63;
                const int nn = n0 + nl;
                const float ig = gsum[nl * 4 + 0][bb];
                const float fg = gsum[nl * 4 + 1][bb];
                const float gg = gsum[nl * 4 + 2][bb];
                const float og = gsum[nl * 4 + 3][bb];
                const size_t cidx = ((size_t)l * NH + nn) * 64 + bb;
                const float iv = 1.0f / (1.0f + __expf(-ig));
                const float fv = 1.0f / (1.0f + __expf(-fg));
                const float gv = tanhf(gg);
                const float ov = 1.0f / (1.0f + __expf(-og));
                const float cn = fv * cbuf[cidx] + iv * gv;
                const float hn = ov * tanhf(cn);
                cbuf[cidx] = cn;
                hcur[cidx] = hn;                   // coalesced
                if (l == NL - 1) outs[((size_t)bb * NT + t) * NH + nn] = hn;
                if (t == NT - 1) {
                    hT[((size_t)l * NB + bb) * NH + nn] = hn;
                    cT[((size_t)l * NB + bb) * NH + nn] = cn;
                }
            }
            grid.sync();
        }
    }
}

extern "C" void kernel_launch(void* const* d_in, const int* in_sizes, int n_in,
                              void* d_out, int out_size, void* d_ws, size_t ws_size,
                              hipStream_t stream) {
    const float* inputs = (const float*)d_in[0];
    const float* enc    = (const float*)d_in[1];
    const float* W_ih   = (const float*)d_in[2];
    const float* W_hh   = (const float*)d_in[3];
    const float* bias   = (const float*)d_in[4];
    float* out  = (float*)d_out;
    float* wsf  = (float*)d_ws;

    const size_t xT_elems  = (size_t)NT * NE * NB;                  // 16.78M
    const size_t need_full = (xT_elems + 3 * (size_t)STATE) * 4;
    const int use_xT = (ws_size >= need_full) ? 1 : 0;

    const float* xT = wsf;
    float* base = use_xT ? wsf + xT_elems : wsf;
    float* h0b  = base;
    float* h1b  = base + STATE;
    float* cbuf = base + 2 * STATE;

    if (use_xT) {
        xpose_kernel<<<dim3(NT * (NE / 64)), dim3(256), 0, stream>>>(inputs, (float*)xT);
    }
    void* args[] = { &inputs, &enc, &W_ih, &W_hh, &bias, &out,
                     &xT, &h0b, &h1b, &cbuf, (void*)&use_xT };
    hipLaunchCooperativeKernel((const void*)lstm_kernel,
                               dim3(NBLK), dim3(NTHR), args, 0, stream);
}

// Round 6
// 60121.722 us; speedup vs baseline: 1.8635x; 1.8635x over previous
//
#include <hip/hip_runtime.h>

static constexpr int NB = 64, NT = 256, NE = 1024, NH = 1024, NL = 3;
static constexpr int NR = 4096;              // gate rows (4H)
static constexpr int STATE = NL * NB * NH;   // 196608
static constexpr int GATES_N = NB * NR;      // 262144 floats = 1 MiB

__device__ __forceinline__ float sigf(float x) { return 1.0f / (1.0f + __expf(-x)); }
__device__ __forceinline__ float tanh_(float x) {
    return 1.0f - 2.0f / (__expf(2.0f * x) + 1.0f);   // exact identity, inf-safe
}

__global__ void __launch_bounds__(512)
init_kernel(const float* __restrict__ enc, float* __restrict__ out,
            float* __restrict__ gates) {
    float* hbA = out;                // hT region doubles as h buffer A
    float* cT  = out + STATE;        // running cell state
    const int idx = blockIdx.x * 512 + threadIdx.x;     // 131072 threads
    for (int i = idx; i < STATE; i += 131072) {
        hbA[i] = enc[i & 65535];     // h0 = tile(enc, L)
        cT[i]  = 0.0f;
    }
    for (int i = idx; i < GATES_N; i += 131072) gates[i] = 0.0f;
}

// grid 512 = 64 row-groups x 8 k-slices; block 512 = 8 waves.
// lane = gate row (64/group), wave = 8 batch rows -> acc[8].
// W: global(coalesced) -> LDS tile[q][r^q] (xor swizzle, conflict-free both ways)
// act: wave-uniform 16B loads (L1 broadcast). Reduce: device atomicAdd.
__global__ void __launch_bounds__(512)
gates_kernel(const float* __restrict__ xbase, long xstr,   // x operand (k<1024)
             const float* __restrict__ hbase,              // h operand (k>=1024)
             const float* __restrict__ wih,                // W_ih + l*NR*NE
             const float* __restrict__ whh,                // W_hh + l*NR*NH
             float* __restrict__ gates)                    // (B,4H) accumulator
{
    const int tid  = threadIdx.x;
    const int lane = tid & 63;
    const int w    = tid >> 6;
    const int bid  = blockIdx.x;
    const int ng   = bid >> 3;       // row group: rows r0..r0+63
    const int ks   = bid & 7;        // k-slice of 256
    const int r0   = ng * 64;
    const int b0   = w * 8;

    __shared__ float4 tile[2][8][64];    // 16 KiB, double-buffered W chunk

    const float* wbase; const float* ab; long astr; int kc0;
    if (ks < 4) { wbase = wih; kc0 = ks * 256;       ab = xbase + kc0; astr = xstr; }
    else        { wbase = whh; kc0 = (ks - 4) * 256; ab = hbase + kc0; astr = 1024; }

    const float* pb[8];
    #pragma unroll
    for (int i = 0; i < 8; ++i) pb[i] = ab + (size_t)(b0 + i) * astr;

    float acc[8] = {0, 0, 0, 0, 0, 0, 0, 0};

    const int sq = tid & 7, sr = tid >> 3;           // staging map
    const float* wrow = wbase + (size_t)(r0 + sr) * 1024 + kc0;
    tile[0][sq][sr ^ sq] = *(const float4*)(wrow + sq * 4);   // chunk 0

    for (int c = 0; c < 8; ++c) {
        __syncthreads();
        if (c + 1 < 8)
            tile[(c + 1) & 1][sq][sr ^ sq] =
                *(const float4*)(wrow + (c + 1) * 32 + sq * 4);
        #pragma unroll
        for (int q = 0; q < 8; ++q) {
            const float4 wq = tile[c & 1][q][lane ^ q];   // = W[r0+lane][..]
            #pragma unroll
            for (int i = 0; i < 8; ++i) {
                const float4 aq = *(const float4*)(pb[i] + c * 32 + q * 4);
                acc[i] = fmaf(aq.x, wq.x, acc[i]);
                acc[i] = fmaf(aq.y, wq.y, acc[i]);
                acc[i] = fmaf(aq.z, wq.z, acc[i]);
                acc[i] = fmaf(aq.w, wq.w, acc[i]);
            }
        }
    }
    #pragma unroll
    for (int i = 0; i < 8; ++i)
        atomicAdd(&gates[((size_t)(b0 + i) << 12) + r0 + lane], acc[i]);
}

// grid 128 x 512: one thread per (b, n). Reads gates+bias, updates c/h,
// resets gates for the next stage.
__global__ void __launch_bounds__(512)
cell_kernel(const float* __restrict__ bias_l, float* __restrict__ gates,
            float* __restrict__ cT_l, float* __restrict__ hcur_l,
            float* __restrict__ outs_t, int is_last)
{
    const int g  = blockIdx.x * 512 + threadIdx.x;   // < 65536
    const int b  = g >> 10, nl = g & 1023;
    float gv[4];
    #pragma unroll
    for (int gi = 0; gi < 4; ++gi) {
        const size_t gidx = ((size_t)b << 12) + gi * 1024 + nl;
        gv[gi] = bias_l[gi * 1024 + nl] + gates[gidx];
        gates[gidx] = 0.0f;                          // reset for next stage
    }
    const int si = b * 1024 + nl;
    const float cn = sigf(gv[1]) * cT_l[si] + sigf(gv[0]) * tanh_(gv[2]);
    const float hn = sigf(gv[3]) * tanh_(cn);
    cT_l[si]   = cn;
    hcur_l[si] = hn;
    if (is_last) outs_t[(size_t)b * (NT * NH) + nl] = hn;
}

extern "C" void kernel_launch(void* const* d_in, const int* in_sizes, int n_in,
                              void* d_out, int out_size, void* d_ws, size_t ws_size,
                              hipStream_t stream) {
    const float* inputs = (const float*)d_in[0];
    const float* enc    = (const float*)d_in[1];
    const float* W_ih   = (const float*)d_in[2];
    const float* W_hh   = (const float*)d_in[3];
    const float* bias   = (const float*)d_in[4];
    float* out = (float*)d_out;
    float* wsf = (float*)d_ws;

    float* gates = wsf;                  // 1 MiB
    float* hbB   = wsf + GATES_N;        // 0.75 MiB  (total 1.75 MiB, proven safe)
    float* hbA   = out;                  // hT region = h buffer A
    float* cT    = out + STATE;
    float* outs  = out + 2 * STATE;

    init_kernel<<<dim3(256), dim3(512), 0, stream>>>(enc, out, gates);

    for (int t = 0; t < NT; ++t) {
        // parity: t=0 reads hbA (init); t=255 (odd) writes hbA == hT region
        float* hprev = (t & 1) ? hbB : hbA;
        float* hcur  = (t & 1) ? hbA : hbB;
        for (int l = 0; l < NL; ++l) {
            const float* xbase; long xstr;
            if (l == 0) { xbase = inputs + (size_t)t * NE;          xstr = (long)NT * NE; }
            else        { xbase = hcur + (size_t)(l - 1) * NB * NH; xstr = NH; }
            gates_kernel<<<dim3(512), dim3(512), 0, stream>>>(
                xbase, xstr,
                hprev + (size_t)l * NB * NH,
                W_ih + (size_t)l * NR * NE,
                W_hh + (size_t)l * NR * NH,
                gates);
            cell_kernel<<<dim3(128), dim3(512), 0, stream>>>(
                bias + (size_t)l * NR, gates,
                cT + (size_t)l * NB * NH,
                hcur + (size_t)l * NB * NH,
                outs + (size_t)t * NH,
                (l == NL - 1) ? 1 : 0);
        }
    }
}

// Round 7
// 35927.933 us; speedup vs baseline: 3.1184x; 1.6734x over previous
//
#include <hip/hip_runtime.h>
#include <hip/hip_cooperative_groups.h>
#include <hip/hip_bf16.h>

namespace cg = cooperative_groups;

using bf16x8 = __attribute__((ext_vector_type(8))) short;  // 8 bf16 in 4 VGPRs
using f32x4  = __attribute__((ext_vector_type(4))) float;

static constexpr int NB = 64, NT = 256, NE = 1024, NH = 1024, NL = 3;
static constexpr int NR = 4096, KC = 2048;
static constexpr int STATE = NL * NB * NH;            // 196608
static constexpr size_t WCAT_E = (size_t)NL * NR * KC; // 25,165,824 bf16
static constexpr size_t XBF_E  = (size_t)NT * NB * NE; // 16,777,216 bf16
static constexpr size_t HBUF_E = (size_t)STATE;        // 196,608 bf16
static constexpr int GATES_N = NB * NR;               // fallback path

// ---------------- bf16 MFMA path ----------------

__global__ void __launch_bounds__(256)
convert_w(const float* __restrict__ wih, const float* __restrict__ whh,
          __hip_bfloat16* __restrict__ wcat) {
    size_t i = (size_t)blockIdx.x * 256 + threadIdx.x;
    const size_t stride = (size_t)gridDim.x * 256;
    for (; i < WCAT_E; i += stride) {
        const int k = (int)(i & (KC - 1));
        const size_t lr = i >> 11;            // l*NR + r
        const int r = (int)(lr & (NR - 1));
        const int l = (int)(lr >> 12);
        const float v = (k < NE) ? wih[((size_t)l * NR + r) * NE + k]
                                 : whh[((size_t)l * NR + r) * NH + (k - NE)];
        wcat[i] = __float2bfloat16(v);
    }
}

__global__ void __launch_bounds__(256)
convert_x(const float* __restrict__ x, __hip_bfloat16* __restrict__ xbf) {
    size_t i = (size_t)blockIdx.x * 256 + threadIdx.x;
    const size_t stride = (size_t)gridDim.x * 256;
    for (; i < XBF_E; i += stride) {          // xbf[t][m][e] <- x[m][t][e]
        const int e = (int)(i & (NE - 1));
        const size_t tm = i >> 10;
        const int m = (int)(tm & (NB - 1));
        const int t = (int)(tm >> 6);
        xbf[i] = __float2bfloat16(x[((size_t)m * NT + t) * NE + e]);
    }
}

__global__ void __launch_bounds__(256)
init_h(const float* __restrict__ enc, __hip_bfloat16* __restrict__ hA) {
    const int i = blockIdx.x * 256 + threadIdx.x;     // 768 blocks: exact
    if (i < STATE) hA[i] = __float2bfloat16(enc[i & (NB * NH - 1)]);
}

// 256 blocks x 256 threads. Block owns 4 hidden units (all 3 layers' worth
// per stage). Wave wv = m-tile (16 batches). Full K=2048 per wave ->
// no reduction. c state in registers. h passed as bf16 via ws buffers.
__global__ void __launch_bounds__(256, 1)
lstm_mfma(const float* __restrict__ bias,
          const __hip_bfloat16* __restrict__ wcat,
          const __hip_bfloat16* __restrict__ xbf,
          __hip_bfloat16* __restrict__ hA,
          __hip_bfloat16* __restrict__ hB,
          float* __restrict__ out)
{
    cg::grid_group grid = cg::this_grid();
    const int tid  = threadIdx.x;
    const int lane = tid & 63;
    const int wv   = tid >> 6;            // m-tile index 0..3
    const int U0   = blockIdx.x * 4;      // first of this block's 4 units
    const int nfr  = lane & 15;           // frag col: g = nfr>>2, u = nfr&3
    const int kgrp = (lane >> 4) * 8;     // frag k-group (8 contiguous)
    const int mrow = wv * 16 + nfr;       // A frag row (batch)

    float* hT   = out;
    float* cT   = out + STATE;
    float* outs = out + 2 * STATE;

    __shared__ float gbuf[4][16][17];     // [m-tile][n][m_local], padded

    // cell-phase thread mapping (fixed across all t -> c in registers)
    const int cu = lane & 3;              // unit offset 0..3
    const int cm = tid >> 2;              // batch 0..63
    const int cunit = U0 + cu;
    float creg[NL] = {0.f, 0.f, 0.f};

    // weight row pointer for this lane's frag col
    const __hip_bfloat16* bbase =
        wcat + ((size_t)((nfr >> 2) * NH + U0 + (nfr & 3))) * KC + kgrp;

    for (int t = 0; t < NT; ++t) {
        const __hip_bfloat16* hprev = (t & 1) ? hB : hA;
        __hip_bfloat16*       hcur  = (t & 1) ? hA : hB;
        for (int l = 0; l < NL; ++l) {
            const __hip_bfloat16* a1 = (l == 0)
                ? xbf + (size_t)t * NB * NE
                : hcur + (size_t)(l - 1) * NB * NH;
            const __hip_bfloat16* a2 = hprev + (size_t)l * NB * NH;
            const __hip_bfloat16* ap1 = a1 + (size_t)mrow * 1024 + kgrp;
            const __hip_bfloat16* ap2 = a2 + (size_t)mrow * 1024 + kgrp;
            const __hip_bfloat16* bp  = bbase + (size_t)l * NR * KC;

            f32x4 acc = {0.f, 0.f, 0.f, 0.f};
            #pragma unroll 8
            for (int k = 0; k < 1024; k += 32)
                acc = __builtin_amdgcn_mfma_f32_16x16x32_bf16(
                        *(const bf16x8*)(ap1 + k), *(const bf16x8*)(bp + k),
                        acc, 0, 0, 0);
            #pragma unroll 8
            for (int k = 0; k < 1024; k += 32)
                acc = __builtin_amdgcn_mfma_f32_16x16x32_bf16(
                        *(const bf16x8*)(ap2 + k), *(const bf16x8*)(bp + 1024 + k),
                        acc, 0, 0, 0);

            const int mgrp = (lane >> 4) * 4;   // D rows: (lane>>4)*4 + j
            #pragma unroll
            for (int j = 0; j < 4; ++j) gbuf[wv][nfr][mgrp + j] = acc[j];
            __syncthreads();

            // cell update for (cm, cunit)
            {
                float gv[4];
                #pragma unroll
                for (int g = 0; g < 4; ++g)
                    gv[g] = gbuf[cm >> 4][g * 4 + cu][cm & 15]
                          + bias[(size_t)l * NR + g * NH + cunit];
                const float iv = 1.f / (1.f + __expf(-gv[0]));
                const float fv = 1.f / (1.f + __expf(-gv[1]));
                const float gg = 1.f - 2.f / (__expf(2.f * gv[2]) + 1.f);
                const float ov = 1.f / (1.f + __expf(-gv[3]));
                const float cn = fv * creg[l] + iv * gg;
                const float hn = ov * (1.f - 2.f / (__expf(2.f * cn) + 1.f));
                creg[l] = cn;
                hcur[(size_t)l * NB * NH + (size_t)cm * NH + cunit] =
                    __float2bfloat16(hn);
                if (l == NL - 1) outs[((size_t)cm * NT + t) * NH + cunit] = hn;
                if (t == NT - 1) {
                    const size_t si = ((size_t)l * NB + cm) * NH + cunit;
                    hT[si] = hn;
                    cT[si] = cn;
                }
            }
            grid.sync();
        }
    }
}

// ---------------- fp32 fallback path (R6, proven) ----------------

__device__ __forceinline__ float sigf(float x) { return 1.0f / (1.0f + __expf(-x)); }
__device__ __forceinline__ float tanh_(float x) {
    return 1.0f - 2.0f / (__expf(2.0f * x) + 1.0f);
}

__global__ void __launch_bounds__(512)
init_kernel(const float* __restrict__ enc, float* __restrict__ out,
            float* __restrict__ gates) {
    float* hbA = out;
    float* cT  = out + STATE;
    const int idx = blockIdx.x * 512 + threadIdx.x;
    for (int i = idx; i < STATE; i += 131072) {
        hbA[i] = enc[i & 65535];
        cT[i]  = 0.0f;
    }
    for (int i = idx; i < GATES_N; i += 131072) gates[i] = 0.0f;
}

__global__ void __launch_bounds__(512)
gates_kernel(const float* __restrict__ xbase, long xstr,
             const float* __restrict__ hbase,
             const float* __restrict__ wih, const float* __restrict__ whh,
             float* __restrict__ gates)
{
    const int tid  = threadIdx.x;
    const int lane = tid & 63;
    const int w    = tid >> 6;
    const int bid  = blockIdx.x;
    const int ng   = bid >> 3;
    const int ks   = bid & 7;
    const int r0   = ng * 64;
    const int b0   = w * 8;

    __shared__ float4 tile[2][8][64];

    const float* wbase; const float* ab; long astr; int kc0;
    if (ks < 4) { wbase = wih; kc0 = ks * 256;       ab = xbase + kc0; astr = xstr; }
    else        { wbase = whh; kc0 = (ks - 4) * 256; ab = hbase + kc0; astr = 1024; }

    const float* pb[8];
    #pragma unroll
    for (int i = 0; i < 8; ++i) pb[i] = ab + (size_t)(b0 + i) * astr;

    float acc[8] = {0, 0, 0, 0, 0, 0, 0, 0};
    const int sq = tid & 7, sr = tid >> 3;
    const float* wrow = wbase + (size_t)(r0 + sr) * 1024 + kc0;
    tile[0][sq][sr ^ sq] = *(const float4*)(wrow + sq * 4);

    for (int c = 0; c < 8; ++c) {
        __syncthreads();
        if (c + 1 < 8)
            tile[(c + 1) & 1][sq][sr ^ sq] =
                *(const float4*)(wrow + (c + 1) * 32 + sq * 4);
        #pragma unroll
        for (int q = 0; q < 8; ++q) {
            const float4 wq = tile[c & 1][q][lane ^ q];
            #pragma unroll
            for (int i = 0; i < 8; ++i) {
                const float4 aq = *(const float4*)(pb[i] + c * 32 + q * 4);
                acc[i] = fmaf(aq.x, wq.x, acc[i]);
                acc[i] = fmaf(aq.y, wq.y, acc[i]);
                acc[i] = fmaf(aq.z, wq.z, acc[i]);
                acc[i] = fmaf(aq.w, wq.w, acc[i]);
            }
        }
    }
    #pragma unroll
    for (int i = 0; i < 8; ++i)
        atomicAdd(&gates[((size_t)(b0 + i) << 12) + r0 + lane], acc[i]);
}

__global__ void __launch_bounds__(512)
cell_kernel(const float* __restrict__ bias_l, float* __restrict__ gates,
            float* __restrict__ cT_l, float* __restrict__ hcur_l,
            float* __restrict__ outs_t, int is_last)
{
    const int g  = blockIdx.x * 512 + threadIdx.x;
    const int b  = g >> 10, nl = g & 1023;
    float gv[4];
    #pragma unroll
    for (int gi = 0; gi < 4; ++gi) {
        const size_t gidx = ((size_t)b << 12) + gi * 1024 + nl;
        gv[gi] = bias_l[gi * 1024 + nl] + gates[gidx];
        gates[gidx] = 0.0f;
    }
    const int si = b * 1024 + nl;
    const float cn = sigf(gv[1]) * cT_l[si] + sigf(gv[0]) * tanh_(gv[2]);
    const float hn = sigf(gv[3]) * tanh_(cn);
    cT_l[si]   = cn;
    hcur_l[si] = hn;
    if (is_last) outs_t[(size_t)b * (NT * NH) + nl] = hn;
}

// ---------------- launcher ----------------

extern "C" void kernel_launch(void* const* d_in, const int* in_sizes, int n_in,
                              void* d_out, int out_size, void* d_ws, size_t ws_size,
                              hipStream_t stream) {
    const float* inputs = (const float*)d_in[0];
    const float* enc    = (const float*)d_in[1];
    const float* W_ih   = (const float*)d_in[2];
    const float* W_hh   = (const float*)d_in[3];
    const float* bias   = (const float*)d_in[4];
    float* out = (float*)d_out;

    const size_t need = (WCAT_E + XBF_E + 2 * HBUF_E) * 2;   // 84,672,512 B
    if (ws_size >= need) {
        __hip_bfloat16* wcat = (__hip_bfloat16*)d_ws;
        __hip_bfloat16* xbf  = wcat + WCAT_E;
        __hip_bfloat16* hA   = xbf + XBF_E;
        __hip_bfloat16* hB   = hA + HBUF_E;

        convert_w<<<dim3(4096), dim3(256), 0, stream>>>(W_ih, W_hh, wcat);
        convert_x<<<dim3(2048), dim3(256), 0, stream>>>(inputs, xbf);
        init_h<<<dim3(768), dim3(256), 0, stream>>>(enc, hA);

        void* args[] = { (void*)&bias, (void*)&wcat, (void*)&xbf,
                         (void*)&hA, (void*)&hB, (void*)&out };
        hipLaunchCooperativeKernel((const void*)lstm_mfma,
                                   dim3(256), dim3(256), args, 0, stream);
    } else {
        float* wsf   = (float*)d_ws;
        float* gates = wsf;
        float* hbB   = wsf + GATES_N;
        float* hbA   = out;
        float* cT    = out + STATE;
        float* outs  = out + 2 * STATE;

        init_kernel<<<dim3(256), dim3(512), 0, stream>>>(enc, out, gates);
        for (int t = 0; t < NT; ++t) {
            float* hprev = (t & 1) ? hbB : hbA;
            float* hcur  = (t & 1) ? hbA : hbB;
            for (int l = 0; l < NL; ++l) {
                const float* xbase; long xstr;
                if (l == 0) { xbase = inputs + (size_t)t * NE;          xstr = (long)NT * NE; }
                else        { xbase = hcur + (size_t)(l - 1) * NB * NH; xstr = NH; }
                gates_kernel<<<dim3(512), dim3(512), 0, stream>>>(
                    xbase, xstr, hprev + (size_t)l * NB * NH,
                    W_ih + (size_t)l * NR * NE, W_hh + (size_t)l * NR * NH, gates);
                cell_kernel<<<dim3(128), dim3(512), 0, stream>>>(
                    bias + (size_t)l * NR, gates,
                    cT + (size_t)l * NB * NH, hcur + (size_t)l * NB * NH,
                    outs + (size_t)t * NH, (l == NL - 1) ? 1 : 0);
            }
        }
    }
}

// Round 10
// 24700.348 us; speedup vs baseline: 4.5359x; 1.4546x over previous
//
#include <hip/hip_runtime.h>
#include <hip/hip_bf16.h>

using bf16x8 = __attribute__((ext_vector_type(8))) short;  // 8 bf16, 4 VGPRs
using f32x4  = __attribute__((ext_vector_type(4))) float;

static constexpr int NB = 64, NT = 256, NE = 1024, NH = 1024, NL = 3;
static constexpr int NR = 4096, KC = 2048;
static constexpr int STATE = NL * NB * NH;             // 196608
static constexpr size_t WCAT_E = (size_t)NL * NR * KC;  // 25,165,824 bf16
static constexpr size_t XBF_E  = (size_t)NT * NB * NE;  // 16,777,216 bf16
static constexpr size_t HBUF_E = (size_t)STATE;
static constexpr int GATES_N = NB * NR;                // fallback path
static constexpr int FLAG_STRIDE = 16;                 // 64B per flag slot
static constexpr size_t FLAGS_W = 256 * FLAG_STRIDE + 8 * FLAG_STRIDE;  // uint32s

// ---------------- prologue kernels ----------------

__global__ void __launch_bounds__(256)
convert_w(const float* __restrict__ wih, const float* __restrict__ whh,
          __hip_bfloat16* __restrict__ wcat) {
    size_t i = (size_t)blockIdx.x * 256 + threadIdx.x;
    const size_t stride = (size_t)gridDim.x * 256;
    for (; i < WCAT_E; i += stride) {
        const int k = (int)(i & (KC - 1));
        const size_t lr = i >> 11;            // l*NR + r
        const int r = (int)(lr & (NR - 1));
        const int l = (int)(lr >> 12);
        const float v = (k < NE) ? wih[((size_t)l * NR + r) * NE + k]
                                 : whh[((size_t)l * NR + r) * NH + (k - NE)];
        wcat[i] = __float2bfloat16(v);
    }
}

__global__ void __launch_bounds__(256)
convert_x(const float* __restrict__ x, __hip_bfloat16* __restrict__ xbf) {
    size_t i = (size_t)blockIdx.x * 256 + threadIdx.x;
    const size_t stride = (size_t)gridDim.x * 256;
    for (; i < XBF_E; i += stride) {          // xbf[t][m][e] <- x[m][t][e]
        const int e = (int)(i & (NE - 1));
        const size_t tm = i >> 10;
        const int m = (int)(tm & (NB - 1));
        const int t = (int)(tm >> 6);
        xbf[i] = __float2bfloat16(x[((size_t)m * NT + t) * NE + e]);
    }
}

__global__ void __launch_bounds__(256)
init_h(const float* __restrict__ enc, __hip_bfloat16* __restrict__ hA,
       unsigned* __restrict__ flags) {
    const int i = blockIdx.x * 256 + threadIdx.x;     // 768 blocks
    if (i < STATE) hA[i] = __float2bfloat16(enc[i & (NB * NH - 1)]);
    if (i < (int)FLAGS_W) flags[i] = 0u;
}

// ---------------- custom two-level barrier ----------------
// flags[bid*16]: per-block generation (64B apart). grp[g*16]: group done.
// 8 checker blocks (bid<8) each watch 32 flags, then post grp; all poll grp.
// Co-residency guaranteed by grid == 256 == #CUs (1 block/CU always fits).
__device__ __forceinline__ void grid_barrier(unsigned* __restrict__ flags,
                                             unsigned* __restrict__ grp,
                                             int bid, int tid, unsigned gen) {
    __syncthreads();
    if (tid == 0) {
        __threadfence();
        __hip_atomic_store(&flags[bid * FLAG_STRIDE], gen,
                           __ATOMIC_RELEASE, __HIP_MEMORY_SCOPE_AGENT);
    }
    const int lane = tid & 63;
    if (bid < 8 && tid < 64) {
        for (;;) {
            unsigned v = gen;
            if (lane < 32)
                v = __hip_atomic_load(&flags[(bid * 32 + lane) * FLAG_STRIDE],
                                      __ATOMIC_RELAXED, __HIP_MEMORY_SCOPE_AGENT);
            if (__all((int)(v >= gen))) break;
            __builtin_amdgcn_s_sleep(1);
        }
        if (lane == 0)
            __hip_atomic_store(&grp[bid * FLAG_STRIDE], gen,
                               __ATOMIC_RELEASE, __HIP_MEMORY_SCOPE_AGENT);
    }
    if (tid < 64) {
        for (;;) {
            const unsigned v =
                __hip_atomic_load(&grp[(lane & 7) * FLAG_STRIDE],
                                  __ATOMIC_RELAXED, __HIP_MEMORY_SCOPE_AGENT);
            if (__all((int)(v >= gen))) break;
            __builtin_amdgcn_s_sleep(1);
        }
    }
    __builtin_amdgcn_fence(__ATOMIC_ACQUIRE, "agent");
    __syncthreads();
}

// ---------------- persistent MFMA kernel (NORMAL launch, grid=256) --------
// Block owns 4 units (all layers). Wave = K-slice of 512, B-frags preloaded
// in registers (b0/b1/b2, constant-indexed). LDS partial reduce + cell.
__global__ void __launch_bounds__(256, 1)
lstm_mfma(const float* __restrict__ bias,
          const __hip_bfloat16* __restrict__ wcat,
          const __hip_bfloat16* __restrict__ xbf,
          __hip_bfloat16* __restrict__ hA,
          __hip_bfloat16* __restrict__ hB,
          float* __restrict__ out,
          unsigned* __restrict__ flags)
{
    const int tid  = threadIdx.x;
    const int lane = tid & 63;
    const int wv   = tid >> 6;            // K-slice 0..3
    const int bid  = blockIdx.x;
    const int U0   = bid * 4;
    const int nfr  = lane & 15;           // frag col: g = nfr>>2, u = nfr&3
    const int kgrp = (lane >> 4) * 8;     // frag k-offset within 32
    const int mgrp = (lane >> 4) * 4;     // D-frag row group
    const int cm   = tid >> 2;            // cell: batch
    const int cu   = tid & 3;             // cell: unit offset
    const int cunit = U0 + cu;

    float* hT   = out;
    float* cT   = out + STATE;
    float* outs = out + 2 * STATE;
    unsigned* grp = flags + 256 * FLAG_STRIDE;

    __shared__ float part[4][4][16][17];  // [kslice][mtile][n][m] padded

    // ---- preload this wave's B fragments for all 3 layers (192 VGPRs) ----
    const int row   = (nfr >> 2) * NH + U0 + (nfr & 3);     // gate row
    const int kbase = (wv >= 2 ? 1024 : 0) + (wv & 1) * 512 + kgrp;
    bf16x8 b0[16], b1[16], b2[16];
    {
        const __hip_bfloat16* w0 = wcat + ((size_t)0 * NR + row) * KC + kbase;
        const __hip_bfloat16* w1 = wcat + ((size_t)1 * NR + row) * KC + kbase;
        const __hip_bfloat16* w2 = wcat + ((size_t)2 * NR + row) * KC + kbase;
        #pragma unroll
        for (int kb = 0; kb < 16; ++kb) {
            b0[kb] = *(const bf16x8*)(w0 + kb * 32);
            b1[kb] = *(const bf16x8*)(w1 + kb * 32);
            b2[kb] = *(const bf16x8*)(w2 + kb * 32);
        }
    }

    float creg0 = 0.f, creg1 = 0.f, creg2 = 0.f;
    unsigned gen = 1;

    // the stage engine as a lambda; all register arrays constant-indexed
    auto stage = [&](const __hip_bfloat16* a1, const __hip_bfloat16* a2,
                     const bf16x8 (&b)[16], const float* bias_l, float& cref,
                     __hip_bfloat16* hcur_l, int t, bool is_top, bool last_t,
                     float* hT_l, float* cT_l) {
        const __hip_bfloat16* apart = (wv < 2) ? a1 : a2;
        const int aoff = (wv & 1) * 512 + kgrp;
        f32x4 acc[4];
        #pragma unroll
        for (int mt = 0; mt < 4; ++mt) acc[mt] = f32x4{0.f, 0.f, 0.f, 0.f};
        #pragma unroll
        for (int mt = 0; mt < 4; ++mt) {
            const __hip_bfloat16* ar = apart + (size_t)(mt * 16 + nfr) * 1024 + aoff;
            #pragma unroll
            for (int kb = 0; kb < 16; ++kb)
                acc[mt] = __builtin_amdgcn_mfma_f32_16x16x32_bf16(
                    *(const bf16x8*)(ar + kb * 32), b[kb], acc[mt], 0, 0, 0);
        }
        #pragma unroll
        for (int mt = 0; mt < 4; ++mt)
            #pragma unroll
            for (int j = 0; j < 4; ++j)
                part[wv][mt][nfr][mgrp + j] = acc[mt][j];
        __syncthreads();

        float gv[4];
        #pragma unroll
        for (int g = 0; g < 4; ++g) {
            float s = bias_l[g * NH + cunit];
            #pragma unroll
            for (int w2 = 0; w2 < 4; ++w2)
                s += part[w2][cm >> 4][g * 4 + cu][cm & 15];
            gv[g] = s;
        }
        const float iv = 1.f / (1.f + __expf(-gv[0]));
        const float fv = 1.f / (1.f + __expf(-gv[1]));
        const float gg = 1.f - 2.f / (__expf(2.f * gv[2]) + 1.f);
        const float ov = 1.f / (1.f + __expf(-gv[3]));
        const float cn = fv * cref + iv * gg;
        const float hn = ov * (1.f - 2.f / (__expf(2.f * cn) + 1.f));
        cref = cn;
        hcur_l[cm * NH + cunit] = __float2bfloat16(hn);
        if (is_top) outs[((size_t)cm * NT + t) * NH + cunit] = hn;
        if (last_t) { hT_l[cm * NH + cunit] = hn; cT_l[cm * NH + cunit] = cn; }
    };

    for (int t = 0; t < NT; ++t) {
        const __hip_bfloat16* hprev = (t & 1) ? hB : hA;
        __hip_bfloat16*       hcur  = (t & 1) ? hA : hB;
        const bool last_t = (t == NT - 1);

        stage(xbf + (size_t)t * NB * NE, hprev, b0, bias, creg0,
              hcur, t, false, last_t, hT, cT);                       // l=0
        grid_barrier(flags, grp, bid, tid, gen++);

        stage(hcur, hprev + NB * NH, b1, bias + NR, creg1,
              hcur + NB * NH, t, false, last_t, hT + NB * NH, cT + NB * NH);
        grid_barrier(flags, grp, bid, tid, gen++);

        stage(hcur + NB * NH, hprev + 2 * NB * NH, b2, bias + 2 * NR, creg2,
              hcur + 2 * NB * NH, t, true, last_t, hT + 2 * NB * NH, cT + 2 * NB * NH);
        if (!last_t) grid_barrier(flags, grp, bid, tid, gen++);
    }
}

// ---------------- fp32 fallback path (R6, proven) ----------------

__device__ __forceinline__ float sigf(float x) { return 1.0f / (1.0f + __expf(-x)); }
__device__ __forceinline__ float tanh_(float x) {
    return 1.0f - 2.0f / (__expf(2.0f * x) + 1.0f);
}

__global__ void __launch_bounds__(512)
init_kernel(const float* __restrict__ enc, float* __restrict__ out,
            float* __restrict__ gates) {
    float* hbA = out;
    float* cTf = out + STATE;
    const int idx = blockIdx.x * 512 + threadIdx.x;
    for (int i = idx; i < STATE; i += 131072) {
        hbA[i] = enc[i & 65535];
        cTf[i] = 0.0f;
    }
    for (int i = idx; i < GATES_N; i += 131072) gates[i] = 0.0f;
}

__global__ void __launch_bounds__(512)
gates_kernel(const float* __restrict__ xbase, long xstr,
             const float* __restrict__ hbase,
             const float* __restrict__ wih, const float* __restrict__ whh,
             float* __restrict__ gates)
{
    const int tid  = threadIdx.x;
    const int lane = tid & 63;
    const int w    = tid >> 6;
    const int bid  = blockIdx.x;
    const int ng   = bid >> 3;
    const int ks   = bid & 7;
    const int r0   = ng * 64;
    const int b0   = w * 8;

    __shared__ float4 tile[2][8][64];

    const float* wbase; const float* ab; long astr; int kc0;
    if (ks < 4) { wbase = wih; kc0 = ks * 256;       ab = xbase + kc0; astr = xstr; }
    else        { wbase = whh; kc0 = (ks - 4) * 256; ab = hbase + kc0; astr = 1024; }

    const float* pb[8];
    #pragma unroll
    for (int i = 0; i < 8; ++i) pb[i] = ab + (size_t)(b0 + i) * astr;

    float acc[8] = {0, 0, 0, 0, 0, 0, 0, 0};
    const int sq = tid & 7, sr = tid >> 3;
    const float* wrow = wbase + (size_t)(r0 + sr) * 1024 + kc0;
    tile[0][sq][sr ^ sq] = *(const float4*)(wrow + sq * 4);

    for (int c = 0; c < 8; ++c) {
        __syncthreads();
        if (c + 1 < 8)
            tile[(c + 1) & 1][sq][sr ^ sq] =
                *(const float4*)(wrow + (c + 1) * 32 + sq * 4);
        #pragma unroll
        for (int q = 0; q < 8; ++q) {
            const float4 wq = tile[c & 1][q][lane ^ q];
            #pragma unroll
            for (int i = 0; i < 8; ++i) {
                const float4 aq = *(const float4*)(pb[i] + c * 32 + q * 4);
                acc[i] = fmaf(aq.x, wq.x, acc[i]);
                acc[i] = fmaf(aq.y, wq.y, acc[i]);
                acc[i] = fmaf(aq.z, wq.z, acc[i]);
                acc[i] = fmaf(aq.w, wq.w, acc[i]);
            }
        }
    }
    #pragma unroll
    for (int i = 0; i < 8; ++i)
        atomicAdd(&gates[((size_t)(b0 + i) << 12) + r0 + lane], acc[i]);
}

__global__ void __launch_bounds__(512)
cell_kernel(const float* __restrict__ bias_l, float* __restrict__ gates,
            float* __restrict__ cT_l, float* __restrict__ hcur_l,
            float* __restrict__ outs_t, int is_last)
{
    const int g  = blockIdx.x * 512 + threadIdx.x;
    const int b  = g >> 10, nl = g & 1023;
    float gv[4];
    #pragma unroll
    for (int gi = 0; gi < 4; ++gi) {
        const size_t gidx = ((size_t)b << 12) + gi * 1024 + nl;
        gv[gi] = bias_l[gi * 1024 + nl] + gates[gidx];
        gates[gidx] = 0.0f;
    }
    const int si = b * 1024 + nl;
    const float cn = sigf(gv[1]) * cT_l[si] + sigf(gv[0]) * tanh_(gv[2]);
    const float hn = sigf(gv[3]) * tanh_(cn);
    cT_l[si]   = cn;
    hcur_l[si] = hn;
    if (is_last) outs_t[(size_t)b * (NT * NH) + nl] = hn;
}

// ---------------- launcher ----------------

extern "C" void kernel_launch(void* const* d_in, const int* in_sizes, int n_in,
                              void* d_out, int out_size, void* d_ws, size_t ws_size,
                              hipStream_t stream) {
    const float* inputs = (const float*)d_in[0];
    const float* enc    = (const float*)d_in[1];
    const float* W_ih   = (const float*)d_in[2];
    const float* W_hh   = (const float*)d_in[3];
    const float* bias   = (const float*)d_in[4];
    float* out = (float*)d_out;

    const size_t need = (WCAT_E + XBF_E + 2 * HBUF_E) * 2 + FLAGS_W * 4;
    if (ws_size >= need) {
        __hip_bfloat16* wcat = (__hip_bfloat16*)d_ws;
        __hip_bfloat16* xbf  = wcat + WCAT_E;
        __hip_bfloat16* hA   = xbf + XBF_E;
        __hip_bfloat16* hB   = hA + HBUF_E;
        unsigned*       flags = (unsigned*)(hB + HBUF_E);

        convert_w<<<dim3(4096), dim3(256), 0, stream>>>(W_ih, W_hh, wcat);
        convert_x<<<dim3(2048), dim3(256), 0, stream>>>(inputs, xbf);
        init_h<<<dim3(768), dim3(256), 0, stream>>>(enc, hA, flags);

        // NORMAL launch: grid == 256 == #CUs -> co-resident by construction.
        lstm_mfma<<<dim3(256), dim3(256), 0, stream>>>(
            bias, wcat, xbf, hA, hB, out, flags);
    } else {
        float* wsf   = (float*)d_ws;
        float* gates = wsf;
        float* hbB   = wsf + GATES_N;
        float* hbA   = out;
        float* cTf   = out + STATE;
        float* outs  = out + 2 * STATE;

        init_kernel<<<dim3(256), dim3(512), 0, stream>>>(enc, out, gates);
        for (int t = 0; t < NT; ++t) {
            float* hprev = (t & 1) ? hbB : hbA;
            float* hcur  = (t & 1) ? hbA : hbB;
            for (int l = 0; l < NL; ++l) {
                const float* xbase; long xstr;
                if (l == 0) { xbase = inputs + (size_t)t * NE;          xstr = (long)NT * NE; }
                else        { xbase = hcur + (size_t)(l - 1) * NB * NH; xstr = NH; }
                gates_kernel<<<dim3(512), dim3(512), 0, stream>>>(
                    xbase, xstr, hprev + (size_t)l * NB * NH,
                    W_ih + (size_t)l * NR * NE, W_hh + (size_t)l * NR * NH, gates);
                cell_kernel<<<dim3(128), dim3(512), 0, stream>>>(
                    bias + (size_t)l * NR, gates,
                    cTf + (size_t)l * NB * NH, hcur + (size_t)l * NB * NH,
                    outs + (size_t)t * NH, (l == NL - 1) ? 1 : 0);
            }
        }
    }
}

// Round 11
// 14617.570 us; speedup vs baseline: 7.6646x; 1.6898x over previous
//
#include <hip/hip_runtime.h>
#include <hip/hip_bf16.h>

using bf16x8 = __attribute__((ext_vector_type(8))) short;  // 8 bf16, 4 VGPRs
using f32x4  = __attribute__((ext_vector_type(4))) float;

static constexpr int NB = 64, NT = 256, NE = 1024, NH = 1024, NL = 3;
static constexpr int NR = 4096, KC = 2048;
static constexpr int STATE = NL * NB * NH;             // 196608
static constexpr size_t WCAT_E = (size_t)NL * NR * KC;  // 25,165,824 bf16
static constexpr size_t XBF_E  = (size_t)NT * NB * NE;  // 16,777,216 bf16
static constexpr size_t HBUF_E = (size_t)STATE;
static constexpr int GATES_N = NB * NR;                // fallback path
static constexpr int FLAG_STRIDE = 16;                 // 64B per flag slot
static constexpr size_t FLAGS_W = 256 * FLAG_STRIDE + 8 * FLAG_STRIDE;  // uint32s

// ---------------- prologue kernels ----------------

__global__ void __launch_bounds__(256)
convert_w(const float* __restrict__ wih, const float* __restrict__ whh,
          __hip_bfloat16* __restrict__ wcat) {
    size_t i = (size_t)blockIdx.x * 256 + threadIdx.x;
    const size_t stride = (size_t)gridDim.x * 256;
    for (; i < WCAT_E; i += stride) {
        const int k = (int)(i & (KC - 1));
        const size_t lr = i >> 11;            // l*NR + r
        const int r = (int)(lr & (NR - 1));
        const int l = (int)(lr >> 12);
        const float v = (k < NE) ? wih[((size_t)l * NR + r) * NE + k]
                                 : whh[((size_t)l * NR + r) * NH + (k - NE)];
        wcat[i] = __float2bfloat16(v);
    }
}

__global__ void __launch_bounds__(256)
convert_x(const float* __restrict__ x, __hip_bfloat16* __restrict__ xbf) {
    size_t i = (size_t)blockIdx.x * 256 + threadIdx.x;
    const size_t stride = (size_t)gridDim.x * 256;
    for (; i < XBF_E; i += stride) {          // xbf[t][m][e] <- x[m][t][e]
        const int e = (int)(i & (NE - 1));
        const size_t tm = i >> 10;
        const int m = (int)(tm & (NB - 1));
        const int t = (int)(tm >> 6);
        xbf[i] = __float2bfloat16(x[((size_t)m * NT + t) * NE + e]);
    }
}

__global__ void __launch_bounds__(256)
init_h(const float* __restrict__ enc, __hip_bfloat16* __restrict__ hA,
       unsigned* __restrict__ flags) {
    const int i = blockIdx.x * 256 + threadIdx.x;     // 768 blocks
    if (i < STATE) hA[i] = __float2bfloat16(enc[i & (NB * NH - 1)]);
    if (i < (int)FLAGS_W) flags[i] = 0u;
}

// ---------------- sc1 (agent write-through / read-through) helpers --------

__device__ __forceinline__ unsigned long long aload64(const void* p) {
    return __hip_atomic_load((const unsigned long long*)p,
                             __ATOMIC_RELAXED, __HIP_MEMORY_SCOPE_AGENT);
}
union FragU { unsigned long long u[2]; bf16x8 v; };
__device__ __forceinline__ bf16x8 aload_frag(const __hip_bfloat16* p) {
    FragU x;
    x.u[0] = aload64(p);
    x.u[1] = aload64(p + 4);
    return x.v;
}
__device__ __forceinline__ unsigned short bf16bits(float f) {
    const __hip_bfloat16 h = __float2bfloat16(f);
    union { __hip_bfloat16 h; unsigned short s; } u{h};
    return u.s;
}

// ---------------- fence-free two-level barrier ----------------
// All shared data moves via sc1 (relaxed agent atomics) -> no wbl2/inv needed.
// Arrival: waitcnt vmcnt(0) (sc1 stores acked at coherence point) -> flag.
__device__ __forceinline__ void grid_barrier(unsigned* __restrict__ flags,
                                             unsigned* __restrict__ grp,
                                             int bid, int tid, unsigned gen) {
    asm volatile("s_waitcnt vmcnt(0)" ::: "memory");
    __syncthreads();
    if (tid == 0) {
        __hip_atomic_store(&flags[bid * FLAG_STRIDE], gen,
                           __ATOMIC_RELAXED, __HIP_MEMORY_SCOPE_AGENT);
    }
    const int lane = tid & 63;
    if (bid < 8 && tid < 64) {
        for (;;) {
            unsigned v = gen;
            if (lane < 32)
                v = __hip_atomic_load(&flags[(bid * 32 + lane) * FLAG_STRIDE],
                                      __ATOMIC_RELAXED, __HIP_MEMORY_SCOPE_AGENT);
            if (__all((int)(v >= gen))) break;
            __builtin_amdgcn_s_sleep(1);
        }
        if (lane == 0)
            __hip_atomic_store(&grp[bid * FLAG_STRIDE], gen,
                               __ATOMIC_RELAXED, __HIP_MEMORY_SCOPE_AGENT);
    }
    if (tid < 64) {
        for (;;) {
            const unsigned v =
                __hip_atomic_load(&grp[(lane & 7) * FLAG_STRIDE],
                                  __ATOMIC_RELAXED, __HIP_MEMORY_SCOPE_AGENT);
            if (__all((int)(v >= gen))) break;
            __builtin_amdgcn_s_sleep(1);
        }
    }
    __syncthreads();
}

// ---------------- persistent MFMA kernel (NORMAL launch, grid=256) --------
// Block owns 4 units. Wave = K-slice of 512, B-frags in registers.
// h-state crosses blocks via sc1 atomics; 2 barriers per t (after l0, l1).
__global__ void __launch_bounds__(256, 1)
lstm_mfma(const float* __restrict__ bias,
          const __hip_bfloat16* __restrict__ wcat,
          const __hip_bfloat16* __restrict__ xbf,
          __hip_bfloat16* __restrict__ hA,
          __hip_bfloat16* __restrict__ hB,
          float* __restrict__ out,
          unsigned* __restrict__ flags)
{
    const int tid  = threadIdx.x;
    const int lane = tid & 63;
    const int wv   = tid >> 6;            // K-slice 0..3
    const int bid  = blockIdx.x;
    const int U0   = bid * 4;
    const int nfr  = lane & 15;           // frag col: g = nfr>>2, u = nfr&3
    const int kgrp = (lane >> 4) * 8;     // frag k-offset within 32
    const int mgrp = (lane >> 4) * 4;     // D-frag row group
    const int cm   = tid >> 1;            // cell: batch (tid<128)
    const int cp   = (tid & 1) * 2;       // cell: unit pair offset (0 or 2)

    float* hT   = out;
    float* cT   = out + STATE;
    float* outs = out + 2 * STATE;
    unsigned* grp = flags + 256 * FLAG_STRIDE;

    __shared__ float part[4][4][16][17];  // [kslice][mtile][n][m] padded

    // ---- preload this wave's B fragments for all 3 layers ----
    const int row   = (nfr >> 2) * NH + U0 + (nfr & 3);     // gate row
    const int kbase = (wv >= 2 ? 1024 : 0) + (wv & 1) * 512 + kgrp;
    bf16x8 b0[16], b1[16], b2[16];
    {
        const __hip_bfloat16* w0 = wcat + ((size_t)0 * NR + row) * KC + kbase;
        const __hip_bfloat16* w1 = wcat + ((size_t)1 * NR + row) * KC + kbase;
        const __hip_bfloat16* w2 = wcat + ((size_t)2 * NR + row) * KC + kbase;
        #pragma unroll
        for (int kb = 0; kb < 16; ++kb) {
            b0[kb] = *(const bf16x8*)(w0 + kb * 32);
            b1[kb] = *(const bf16x8*)(w1 + kb * 32);
            b2[kb] = *(const bf16x8*)(w2 + kb * 32);
        }
    }

    float c0a = 0.f, c0b = 0.f, c1a = 0.f, c1b = 0.f, c2a = 0.f, c2b = 0.f;
    unsigned gen = 1;

    // stage engine: a1 used by waves 0,1 (cached iff layer 0 = xbf),
    // a2 (always h, sc1) by waves 2,3.
    auto stage = [&](const __hip_bfloat16* a1, const __hip_bfloat16* a2,
                     bool a1cached, const bf16x8 (&b)[16], const float* bias_l,
                     float& cA, float& cB, __hip_bfloat16* hcur_l,
                     int t, bool is_top, bool last_t,
                     float* hT_l, float* cT_l) {
        const __hip_bfloat16* apart = (wv < 2) ? a1 : a2;
        const bool cached = (wv < 2) ? a1cached : false;
        const int aoff = (wv & 1) * 512 + kgrp;
        f32x4 acc[4];
        #pragma unroll
        for (int mt = 0; mt < 4; ++mt) acc[mt] = f32x4{0.f, 0.f, 0.f, 0.f};
        if (cached) {
            #pragma unroll
            for (int mt = 0; mt < 4; ++mt) {
                const __hip_bfloat16* ar = apart + (size_t)(mt * 16 + nfr) * 1024 + aoff;
                #pragma unroll
                for (int kb = 0; kb < 16; ++kb)
                    acc[mt] = __builtin_amdgcn_mfma_f32_16x16x32_bf16(
                        *(const bf16x8*)(ar + kb * 32), b[kb], acc[mt], 0, 0, 0);
            }
        } else {
            #pragma unroll
            for (int mt = 0; mt < 4; ++mt) {
                const __hip_bfloat16* ar = apart + (size_t)(mt * 16 + nfr) * 1024 + aoff;
                #pragma unroll
                for (int kb = 0; kb < 16; ++kb)
                    acc[mt] = __builtin_amdgcn_mfma_f32_16x16x32_bf16(
                        aload_frag(ar + kb * 32), b[kb], acc[mt], 0, 0, 0);
            }
        }
        #pragma unroll
        for (int mt = 0; mt < 4; ++mt)
            #pragma unroll
            for (int j = 0; j < 4; ++j)
                part[wv][mt][nfr][mgrp + j] = acc[mt][j];
        __syncthreads();

        if (tid < 128) {                   // 2 adjacent units per thread
            float hn2[2], cn2[2];
            #pragma unroll
            for (int j = 0; j < 2; ++j) {
                const int ul = cp + j;
                const int cunit = U0 + ul;
                float gv[4];
                #pragma unroll
                for (int g = 0; g < 4; ++g) {
                    float s = bias_l[g * NH + cunit];
                    #pragma unroll
                    for (int w2 = 0; w2 < 4; ++w2)
                        s += part[w2][cm >> 4][g * 4 + ul][cm & 15];
                    gv[g] = s;
                }
                const float iv = 1.f / (1.f + __expf(-gv[0]));
                const float fv = 1.f / (1.f + __expf(-gv[1]));
                const float gg = 1.f - 2.f / (__expf(2.f * gv[2]) + 1.f);
                const float ov = 1.f / (1.f + __expf(-gv[3]));
                float& cref = (j == 0) ? cA : cB;
                const float cn = fv * cref + iv * gg;
                const float hn = ov * (1.f - 2.f / (__expf(2.f * cn) + 1.f));
                cref = cn;
                hn2[j] = hn; cn2[j] = cn;
            }
            // packed write-through store (2 bf16 -> uint32, sc1)
            const unsigned pk = (unsigned)bf16bits(hn2[0]) |
                                ((unsigned)bf16bits(hn2[1]) << 16);
            __hip_atomic_store((unsigned*)(hcur_l + cm * NH + U0 + cp), pk,
                               __ATOMIC_RELAXED, __HIP_MEMORY_SCOPE_AGENT);
            if (is_top) {
                outs[((size_t)cm * NT + t) * NH + U0 + cp]     = hn2[0];
                outs[((size_t)cm * NT + t) * NH + U0 + cp + 1] = hn2[1];
            }
            if (last_t) {
                hT_l[cm * NH + U0 + cp]     = hn2[0];
                hT_l[cm * NH + U0 + cp + 1] = hn2[1];
                cT_l[cm * NH + U0 + cp]     = cn2[0];
                cT_l[cm * NH + U0 + cp + 1] = cn2[1];
            }
        }
    };

    for (int t = 0; t < NT; ++t) {
        const __hip_bfloat16* hprev = (t & 1) ? hB : hA;
        __hip_bfloat16*       hcur  = (t & 1) ? hA : hB;
        const bool last_t = (t == NT - 1);

        stage(xbf + (size_t)t * NB * NE, hprev, true, b0, bias,
              c0a, c0b, hcur, t, false, last_t, hT, cT);             // l=0
        grid_barrier(flags, grp, bid, tid, gen++);

        stage(hcur, hprev + NB * NH, false, b1, bias + NR,
              c1a, c1b, hcur + NB * NH, t, false, last_t,
              hT + NB * NH, cT + NB * NH);                           // l=1
        grid_barrier(flags, grp, bid, tid, gen++);

        stage(hcur + NB * NH, hprev + 2 * NB * NH, false, b2, bias + 2 * NR,
              c2a, c2b, hcur + 2 * NB * NH, t, true, last_t,
              hT + 2 * NB * NH, cT + 2 * NB * NH);                   // l=2
        // no barrier after l=2: next readers/writers of these buffers are
        // separated by the t+1 l0/l1 barriers (RAW/WAR verified on parity).
    }
}

// ---------------- fp32 fallback path (R6, proven) ----------------

__device__ __forceinline__ float sigf(float x) { return 1.0f / (1.0f + __expf(-x)); }
__device__ __forceinline__ float tanh_(float x) {
    return 1.0f - 2.0f / (__expf(2.0f * x) + 1.0f);
}

__global__ void __launch_bounds__(512)
init_kernel(const float* __restrict__ enc, float* __restrict__ out,
            float* __restrict__ gates) {
    float* hbA = out;
    float* cTf = out + STATE;
    const int idx = blockIdx.x * 512 + threadIdx.x;
    for (int i = idx; i < STATE; i += 131072) {
        hbA[i] = enc[i & 65535];
        cTf[i] = 0.0f;
    }
    for (int i = idx; i < GATES_N; i += 131072) gates[i] = 0.0f;
}

__global__ void __launch_bounds__(512)
gates_kernel(const float* __restrict__ xbase, long xstr,
             const float* __restrict__ hbase,
             const float* __restrict__ wih, const float* __restrict__ whh,
             float* __restrict__ gates)
{
    const int tid  = threadIdx.x;
    const int lane = tid & 63;
    const int w    = tid >> 6;
    const int bid  = blockIdx.x;
    const int ng   = bid >> 3;
    const int ks   = bid & 7;
    const int r0   = ng * 64;
    const int b0   = w * 8;

    __shared__ float4 tile[2][8][64];

    const float* wbase; const float* ab; long astr; int kc0;
    if (ks < 4) { wbase = wih; kc0 = ks * 256;       ab = xbase + kc0; astr = xstr; }
    else        { wbase = whh; kc0 = (ks - 4) * 256; ab = hbase + kc0; astr = 1024; }

    const float* pb[8];
    #pragma unroll
    for (int i = 0; i < 8; ++i) pb[i] = ab + (size_t)(b0 + i) * astr;

    float acc[8] = {0, 0, 0, 0, 0, 0, 0, 0};
    const int sq = tid & 7, sr = tid >> 3;
    const float* wrow = wbase + (size_t)(r0 + sr) * 1024 + kc0;
    tile[0][sq][sr ^ sq] = *(const float4*)(wrow + sq * 4);

    for (int c = 0; c < 8; ++c) {
        __syncthreads();
        if (c + 1 < 8)
            tile[(c + 1) & 1][sq][sr ^ sq] =
                *(const float4*)(wrow + (c + 1) * 32 + sq * 4);
        #pragma unroll
        for (int q = 0; q < 8; ++q) {
            const float4 wq = tile[c & 1][q][lane ^ q];
            #pragma unroll
            for (int i = 0; i < 8; ++i) {
                const float4 aq = *(const float4*)(pb[i] + c * 32 + q * 4);
                acc[i] = fmaf(aq.x, wq.x, acc[i]);
                acc[i] = fmaf(aq.y, wq.y, acc[i]);
                acc[i] = fmaf(aq.z, wq.z, acc[i]);
                acc[i] = fmaf(aq.w, wq.w, acc[i]);
            }
        }
    }
    #pragma unroll
    for (int i = 0; i < 8; ++i)
        atomicAdd(&gates[((size_t)(b0 + i) << 12) + r0 + lane], acc[i]);
}

__global__ void __launch_bounds__(512)
cell_kernel(const float* __restrict__ bias_l, float* __restrict__ gates,
            float* __restrict__ cT_l, float* __restrict__ hcur_l,
            float* __restrict__ outs_t, int is_last)
{
    const int g  = blockIdx.x * 512 + threadIdx.x;
    const int b  = g >> 10, nl = g & 1023;
    float gv[4];
    #pragma unroll
    for (int gi = 0; gi < 4; ++gi) {
        const size_t gidx = ((size_t)b << 12) + gi * 1024 + nl;
        gv[gi] = bias_l[gi * 1024 + nl] + gates[gidx];
        gates[gidx] = 0.0f;
    }
    const int si = b * 1024 + nl;
    const float cn = sigf(gv[1]) * cT_l[si] + sigf(gv[0]) * tanh_(gv[2]);
    const float hn = sigf(gv[3]) * tanh_(cn);
    cT_l[si]   = cn;
    hcur_l[si] = hn;
    if (is_last) outs_t[(size_t)b * (NT * NH) + nl] = hn;
}

// ---------------- launcher ----------------

extern "C" void kernel_launch(void* const* d_in, const int* in_sizes, int n_in,
                              void* d_out, int out_size, void* d_ws, size_t ws_size,
                              hipStream_t stream) {
    const float* inputs = (const float*)d_in[0];
    const float* enc    = (const float*)d_in[1];
    const float* W_ih   = (const float*)d_in[2];
    const float* W_hh   = (const float*)d_in[3];
    const float* bias   = (const float*)d_in[4];
    float* out = (float*)d_out;

    const size_t need = (WCAT_E + XBF_E + 2 * HBUF_E) * 2 + FLAGS_W * 4;
    if (ws_size >= need) {
        __hip_bfloat16* wcat = (__hip_bfloat16*)d_ws;
        __hip_bfloat16* xbf  = wcat + WCAT_E;
        __hip_bfloat16* hA   = xbf + XBF_E;
        __hip_bfloat16* hB   = hA + HBUF_E;
        unsigned*       flags = (unsigned*)(hB + HBUF_E);

        convert_w<<<dim3(4096), dim3(256), 0, stream>>>(W_ih, W_hh, wcat);
        convert_x<<<dim3(2048), dim3(256), 0, stream>>>(inputs, xbf);
        init_h<<<dim3(768), dim3(256), 0, stream>>>(enc, hA, flags);

        // NORMAL launch: grid == 256 == #CUs -> co-resident by construction.
        lstm_mfma<<<dim3(256), dim3(256), 0, stream>>>(
            bias, wcat, xbf, hA, hB, out, flags);
    } else {
        float* wsf   = (float*)d_ws;
        float* gates = wsf;
        float* hbB   = wsf + GATES_N;
        float* hbA   = out;
        float* cTf   = out + STATE;
        float* outs  = out + 2 * STATE;

        init_kernel<<<dim3(256), dim3(512), 0, stream>>>(enc, out, gates);
        for (int t = 0; t < NT; ++t) {
            float* hprev = (t & 1) ? hbB : hbA;
            float* hcur  = (t & 1) ? hbA : hbB;
            for (int l = 0; l < NL; ++l) {
                const float* xbase; long xstr;
                if (l == 0) { xbase = inputs + (size_t)t * NE;          xstr = (long)NT * NE; }
                else        { xbase = hcur + (size_t)(l - 1) * NB * NH; xstr = NH; }
                gates_kernel<<<dim3(512), dim3(512), 0, stream>>>(
                    xbase, xstr, hprev + (size_t)l * NB * NH,
                    W_ih + (size_t)l * NR * NE, W_hh + (size_t)l * NR * NH, gates);
                cell_kernel<<<dim3(128), dim3(512), 0, stream>>>(
                    bias + (size_t)l * NR, gates,
                    cTf + (size_t)l * NB * NH, hcur + (size_t)l * NB * NH,
                    outs + (size_t)t * NH, (l == NL - 1) ? 1 : 0);
            }
        }
    }
}